// Round 1
// baseline (3131.974 us; speedup 1.0000x reference)
//
#include <hip/hip_runtime.h>
#include <hip/hip_fp16.h>

typedef _Float16 half8 __attribute__((ext_vector_type(8)));
typedef float f32x4 __attribute__((ext_vector_type(4)));

// ---------------- small utility kernels ----------------

__global__ void to_f16_kernel(const float* __restrict__ A, _Float16* __restrict__ B, int n) {
  int i = blockIdx.x * 256 + threadIdx.x;
  if (i < n) B[i] = (_Float16)A[i];
}

// WT[n*K+k] = W[k*N+n]  (weights stored transposed so GEMM B-staging is coalesced)
__global__ void transpose_f16_kernel(const float* __restrict__ W, _Float16* __restrict__ WT, int K, int N) {
  int i = blockIdx.x * 256 + threadIdx.x;
  if (i >= K * N) return;
  int n = i / K, k = i - n * K;
  WT[i] = (_Float16)W[(size_t)k * N + n];
}

__global__ void transpose_f32_kernel(const float* __restrict__ W, float* __restrict__ WT, int K, int N) {
  int i = blockIdx.x * 256 + threadIdx.x;
  if (i >= K * N) return;
  int n = i / K, k = i - n * K;
  WT[i] = W[(size_t)k * N + n];
}

// in-degree histogram + per-dst edge_attr sum (for self-loop fill_value='mean')
__global__ void edge_hist_kernel(const int* __restrict__ dst0, const float* __restrict__ ea,
                                 int* __restrict__ deg, float* __restrict__ lsum, int E) {
  int i = blockIdx.x * 256 + threadIdx.x;
  if (i >= E * 16) return;
  int e = i >> 4, k = i & 15;
  int d = dst0[e];
  if (k == 0) atomicAdd(&deg[d], 1);
  atomicAdd(&lsum[(size_t)d * 16 + k], ea[i]);
}

__global__ void loop_norm_kernel(const float* __restrict__ lsum, const int* __restrict__ deg,
                                 float* __restrict__ lattr, int N) {
  int i = blockIdx.x * 256 + threadIdx.x;
  if (i >= N * 16) return;
  float c = (float)deg[i >> 4];
  lattr[i] = lsum[i] / fmaxf(c, 1.0f);
}

// exclusive scan of (deg[v]+1) -> offs[0..N], single block
__global__ __launch_bounds__(1024) void scan_kernel(const int* __restrict__ deg, int* __restrict__ offs, int N) {
  __shared__ int part[1024];
  int t = threadIdx.x;
  int chunk = (N + 1023) / 1024;
  int b = t * chunk, e = min(b + chunk, N);
  int s = 0;
  for (int i = b; i < e; i++) s += deg[i] + 1;
  part[t] = s;
  __syncthreads();
  for (int off = 1; off < 1024; off <<= 1) {
    int v = (t >= off) ? part[t - off] : 0;
    __syncthreads();
    part[t] += v;
    __syncthreads();
  }
  int run = (t == 0) ? 0 : part[t - 1];
  for (int i = b; i < e; i++) { offs[i] = run; run += deg[i] + 1; }
  if (t == 1023) offs[N] = part[1023];
}

// scatter real edges into CSR buckets; self-loop edge id E+v appended at slot offs[v]+deg[v]
__global__ void csr_fill_kernel(const int* __restrict__ dst0, const int* __restrict__ offs,
                                const int* __restrict__ deg, int* __restrict__ cnt,
                                int* __restrict__ csr, int E, int N) {
  int i = blockIdx.x * 256 + threadIdx.x;
  if (i < E) {
    int d = dst0[i];
    int p = offs[d] + atomicAdd(&cnt[d], 1);
    csr[p] = i;
  } else if (i < E + N) {
    int v = i - E;
    csr[offs[v] + deg[v]] = E + v;
  }
}

// ---------------- GEMM: C[M,N] = A[M,K](f16) * B (given as BT[N,K] f16) + bias ----------------
// 128x128 tile, 4 waves (2x2), each wave 64x64 via 4x4 mfma_f32_16x16x32_f16.
template <bool RELU, bool OUT_F32>
__global__ __launch_bounds__(256) void gemm_f16(const _Float16* __restrict__ A,
                                                const _Float16* __restrict__ BT,
                                                const float* __restrict__ bias,
                                                void* __restrict__ C,
                                                int M, int K, int Nfull) {
  __shared__ _Float16 As[128 * 40];  // row stride 40 halves (80B, keeps 16B align, breaks bank stride)
  __shared__ _Float16 Bs[128 * 40];
  int t = threadIdx.x;
  int m0 = blockIdx.x * 128;
  int n0 = blockIdx.y * 128;
  int l = t & 63, w = t >> 6;
  int wm = w & 1, wn = w >> 1;
  int lr = l & 15, lq = l >> 4;

  f32x4 acc[4][4];
#pragma unroll
  for (int i = 0; i < 4; i++)
#pragma unroll
    for (int j = 0; j < 4; j++) acc[i][j] = (f32x4){0.f, 0.f, 0.f, 0.f};

  const half8 hzero = {0, 0, 0, 0, 0, 0, 0, 0};
  int srow = t >> 2;            // staging row 0..63 (+64 for second chunk)
  int sq = (t & 3) * 8;         // staging k-offset in halves

  for (int kk = 0; kk < K; kk += 32) {
    half8 a0 = (m0 + srow < M) ? *(const half8*)(A + (size_t)(m0 + srow) * K + kk + sq) : hzero;
    half8 a1 = (m0 + srow + 64 < M) ? *(const half8*)(A + (size_t)(m0 + srow + 64) * K + kk + sq) : hzero;
    half8 b0 = (n0 + srow < Nfull) ? *(const half8*)(BT + (size_t)(n0 + srow) * K + kk + sq) : hzero;
    half8 b1 = (n0 + srow + 64 < Nfull) ? *(const half8*)(BT + (size_t)(n0 + srow + 64) * K + kk + sq) : hzero;
    __syncthreads();
    *(half8*)&As[srow * 40 + sq] = a0;
    *(half8*)&As[(srow + 64) * 40 + sq] = a1;
    *(half8*)&Bs[srow * 40 + sq] = b0;
    *(half8*)&Bs[(srow + 64) * 40 + sq] = b1;
    __syncthreads();
    half8 af[4], bf[4];
#pragma unroll
    for (int mi = 0; mi < 4; mi++) af[mi] = *(const half8*)&As[(wm * 64 + mi * 16 + lr) * 40 + lq * 8];
#pragma unroll
    for (int ni = 0; ni < 4; ni++) bf[ni] = *(const half8*)&Bs[(wn * 64 + ni * 16 + lr) * 40 + lq * 8];
#pragma unroll
    for (int mi = 0; mi < 4; mi++)
#pragma unroll
      for (int ni = 0; ni < 4; ni++)
        acc[mi][ni] = __builtin_amdgcn_mfma_f32_16x16x32_f16(af[mi], bf[ni], acc[mi][ni], 0, 0, 0);
  }

#pragma unroll
  for (int ni = 0; ni < 4; ni++) {
    int col = n0 + wn * 64 + ni * 16 + lr;
    if (col >= Nfull) continue;
    float bv = bias[col];
#pragma unroll
    for (int mi = 0; mi < 4; mi++) {
#pragma unroll
      for (int r = 0; r < 4; r++) {
        int row = m0 + wm * 64 + mi * 16 + lq * 4 + r;
        if (row >= M) continue;
        float v = acc[mi][ni][r] + bv;
        if (RELU) v = fmaxf(v, 0.f);
        if (OUT_F32) ((float*)C)[(size_t)row * Nfull + col] = v;
        else ((_Float16*)C)[(size_t)row * Nfull + col] = (_Float16)v;
      }
    }
  }
}

// ---------------- edge logits: one wave per edge ----------------
// logits[e,h] = sum_c att[h,c] * lrelu(xl[src,h,c] + xr[dst,h,c] + (ea[e] @ We)[h,c])
__global__ __launch_bounds__(256) void logits_kernel(
    const _Float16* __restrict__ xl, const _Float16* __restrict__ xr,
    const int* __restrict__ src0, const int* __restrict__ dst0,
    const float* __restrict__ ea, const float* __restrict__ lattr,
    const float* __restrict__ WeT, const float* __restrict__ att,
    float* __restrict__ logits, int E, int EP) {
  int l = threadIdx.x & 63;
  int e = blockIdx.x * 4 + (threadIdx.x >> 6);
  if (e >= EP) return;
  int s, d;
  const float* eap;
  if (e < E) { s = src0[e]; d = dst0[e]; eap = ea + (size_t)e * 16; }
  else { s = e - E; d = s; eap = lattr + (size_t)s * 16; }
  int c0 = l * 8;  // 8 consecutive channels per lane; head = l>>4
  half8 a = *(const half8*)(xl + (size_t)s * 512 + c0);
  half8 b = *(const half8*)(xr + (size_t)d * 512 + c0);
  float eav[16];
#pragma unroll
  for (int k = 0; k < 16; k++) eav[k] = eap[k];
  int h = l >> 4;
  const float* attp = att + h * 128 + (l & 15) * 8;
  float partial = 0.f;
#pragma unroll
  for (int j = 0; j < 8; j++) {
    const float* wr = WeT + (size_t)(c0 + j) * 16;  // WeT[c][k]
    float ef = 0.f;
#pragma unroll
    for (int k = 0; k < 16; k++) ef += eav[k] * wr[k];
    float v = (float)a[j] + (float)b[j] + ef;
    v = v > 0.f ? v : 0.2f * v;
    partial += v * attp[j];
  }
#pragma unroll
  for (int off = 1; off < 16; off <<= 1) partial += __shfl_xor(partial, off);
  if ((l & 15) == 0) logits[(size_t)e * 4 + h] = partial;
}

// per-(node,head) softmax max and 1/denominator
__global__ void stats_kernel(const float* __restrict__ logits, const int* __restrict__ csr,
                             const int* __restrict__ offs, float* __restrict__ mx,
                             float* __restrict__ rden, int N) {
  int i = blockIdx.x * 256 + threadIdx.x;
  if (i >= N * 4) return;
  int v = i >> 2, h = i & 3;
  int b = offs[v], e = offs[v + 1];
  float m = -1e30f;
  for (int j = b; j < e; j++) m = fmaxf(m, logits[(size_t)csr[j] * 4 + h]);
  float s = 0.f;
  for (int j = b; j < e; j++) s += __expf(logits[(size_t)csr[j] * 4 + h] - m);
  mx[i] = m;
  rden[i] = 1.0f / (s + 1e-16f);
}

// block-per-node weighted aggregation: h[v,t] = sum_e alpha[e,h] * xl[src(e),t] + bias[t]
__global__ __launch_bounds__(512) void aggregate_kernel(
    const _Float16* __restrict__ xl, const float* __restrict__ logits,
    const float* __restrict__ mx, const float* __restrict__ rden,
    const int* __restrict__ csr, const int* __restrict__ offs,
    const int* __restrict__ src0, const float* __restrict__ bias,
    _Float16* __restrict__ hout, int E) {
  int v = blockIdx.x, t = threadIdx.x;
  int b = offs[v], e = offs[v + 1];
  int h = t >> 7;
  __shared__ float s_a[64 * 4];
  __shared__ int s_s[64];
  float acc = 0.f;
  for (int base = b; base < e; base += 64) {
    int cnt = min(64, e - base);
    if (t < cnt * 4) {
      int j = t >> 2, hh = t & 3;
      int eid = csr[base + j];
      float al = __expf(logits[(size_t)eid * 4 + hh] - mx[v * 4 + hh]) * rden[v * 4 + hh];
      s_a[j * 4 + hh] = al;
      if (hh == 0) s_s[j] = (eid < E) ? src0[eid] : v;
    }
    __syncthreads();
    for (int j = 0; j < cnt; j++)
      acc += s_a[j * 4 + h] * (float)xl[(size_t)s_s[j] * 512 + t];
    __syncthreads();
  }
  hout[(size_t)v * 512 + t] = (_Float16)(acc + bias[t]);
}

// ---------------- launcher ----------------

extern "C" void kernel_launch(void* const* d_in, const int* in_sizes, int n_in,
                              void* d_out, int out_size, void* d_ws, size_t ws_size,
                              hipStream_t stream) {
  (void)n_in; (void)out_size; (void)ws_size;
  const float* x    = (const float*)d_in[0];
  const int*   ei   = (const int*)d_in[1];
  const float* ea   = (const float*)d_in[2];
  const float* Wl1  = (const float*)d_in[3];
  const float* bl1  = (const float*)d_in[4];
  const float* Wr1  = (const float*)d_in[5];
  const float* br1  = (const float*)d_in[6];
  const float* We1  = (const float*)d_in[7];
  const float* att1 = (const float*)d_in[8];
  const float* bias1= (const float*)d_in[9];
  const float* Wl2  = (const float*)d_in[10];
  const float* bl2  = (const float*)d_in[11];
  const float* Wr2  = (const float*)d_in[12];
  const float* br2  = (const float*)d_in[13];
  const float* We2  = (const float*)d_in[14];
  const float* att2 = (const float*)d_in[15];
  const float* bias2= (const float*)d_in[16];
  const float* Wd1  = (const float*)d_in[17];
  const float* bd1  = (const float*)d_in[18];
  const float* Wd2  = (const float*)d_in[19];
  const float* bd2  = (const float*)d_in[20];

  const int N = in_sizes[0] / 128;
  const int E = in_sizes[1] / 2;
  const int EP = E + N;
  const int* src0 = ei;
  const int* dst0 = ei + E;

  char* ws = (char*)d_ws;
  size_t off = 0;
  auto alloc = [&](size_t bytes) -> void* {
    void* p = ws + off;
    off += (bytes + 255) & ~(size_t)255;
    return p;
  };

  // deg | cnt | lsum contiguous -> single memset
  int*   deg   = (int*)alloc((size_t)N * 72);
  int*   cnt   = deg + N;
  float* lsum  = (float*)(cnt + N);
  int*   offs  = (int*)alloc(((size_t)N + 1) * 4);
  int*   csr   = (int*)alloc((size_t)EP * 4);
  float* lattr = (float*)alloc((size_t)N * 64);
  float* logits= (float*)alloc((size_t)EP * 16);
  float* mx    = (float*)alloc((size_t)N * 16);
  float* rden  = (float*)alloc((size_t)N * 16);
  _Float16* x16  = (_Float16*)alloc((size_t)N * 128 * 2);
  _Float16* xl16 = (_Float16*)alloc((size_t)N * 512 * 2);
  _Float16* xr16 = (_Float16*)alloc((size_t)N * 512 * 2);
  _Float16* h16  = (_Float16*)alloc((size_t)N * 512 * 2);
  _Float16* WlT1 = (_Float16*)alloc(128 * 512 * 2);
  _Float16* WrT1 = (_Float16*)alloc(128 * 512 * 2);
  _Float16* WlT2 = (_Float16*)alloc(512 * 512 * 2);
  _Float16* WrT2 = (_Float16*)alloc(512 * 512 * 2);
  _Float16* WdT1 = (_Float16*)alloc(512 * 512 * 2);
  _Float16* WdT2 = (_Float16*)alloc(512 * 64 * 2);
  float* WeT1 = (float*)alloc(16 * 512 * 4);
  float* WeT2 = (float*)alloc(16 * 512 * 4);
  _Float16* t16 = xr16;  // decoder hidden reuses xr buffer (dead by then)

  hipMemsetAsync(deg, 0, (size_t)N * 72, stream);

  int g;
  g = (N * 128 + 255) / 256; to_f16_kernel<<<g, 256, 0, stream>>>(x, x16, N * 128);
  g = (128 * 512 + 255) / 256;
  transpose_f16_kernel<<<g, 256, 0, stream>>>(Wl1, WlT1, 128, 512);
  transpose_f16_kernel<<<g, 256, 0, stream>>>(Wr1, WrT1, 128, 512);
  g = (512 * 512 + 255) / 256;
  transpose_f16_kernel<<<g, 256, 0, stream>>>(Wl2, WlT2, 512, 512);
  transpose_f16_kernel<<<g, 256, 0, stream>>>(Wr2, WrT2, 512, 512);
  transpose_f16_kernel<<<g, 256, 0, stream>>>(Wd1, WdT1, 512, 512);
  g = (512 * 64 + 255) / 256;
  transpose_f16_kernel<<<g, 256, 0, stream>>>(Wd2, WdT2, 512, 64);
  g = (16 * 512 + 255) / 256;
  transpose_f32_kernel<<<g, 256, 0, stream>>>(We1, WeT1, 16, 512);
  transpose_f32_kernel<<<g, 256, 0, stream>>>(We2, WeT2, 16, 512);

  dim3 gg((N + 127) / 128, 4), gb(256);
  gemm_f16<false, false><<<gg, gb, 0, stream>>>(x16, WlT1, bl1, xl16, N, 128, 512);
  gemm_f16<false, false><<<gg, gb, 0, stream>>>(x16, WrT1, br1, xr16, N, 128, 512);

  g = (E * 16 + 255) / 256; edge_hist_kernel<<<g, 256, 0, stream>>>(dst0, ea, deg, lsum, E);
  g = (N * 16 + 255) / 256; loop_norm_kernel<<<g, 256, 0, stream>>>(lsum, deg, lattr, N);
  scan_kernel<<<1, 1024, 0, stream>>>(deg, offs, N);
  g = (EP + 255) / 256; csr_fill_kernel<<<g, 256, 0, stream>>>(dst0, offs, deg, cnt, csr, E, N);

  // ---- GAT layer 1 ----
  g = (EP + 3) / 4;
  logits_kernel<<<g, 256, 0, stream>>>(xl16, xr16, src0, dst0, ea, lattr, WeT1, att1, logits, E, EP);
  g = (N * 4 + 255) / 256; stats_kernel<<<g, 256, 0, stream>>>(logits, csr, offs, mx, rden, N);
  aggregate_kernel<<<N, 512, 0, stream>>>(xl16, logits, mx, rden, csr, offs, src0, bias1, h16, E);

  // ---- GAT layer 2 ----
  gemm_f16<false, false><<<gg, gb, 0, stream>>>(h16, WlT2, bl2, xl16, N, 512, 512);
  gemm_f16<false, false><<<gg, gb, 0, stream>>>(h16, WrT2, br2, xr16, N, 512, 512);
  g = (EP + 3) / 4;
  logits_kernel<<<g, 256, 0, stream>>>(xl16, xr16, src0, dst0, ea, lattr, WeT2, att2, logits, E, EP);
  g = (N * 4 + 255) / 256; stats_kernel<<<g, 256, 0, stream>>>(logits, csr, offs, mx, rden, N);
  aggregate_kernel<<<N, 512, 0, stream>>>(xl16, logits, mx, rden, csr, offs, src0, bias2, h16, E);

  // ---- decoder ----
  gemm_f16<true, false><<<gg, gb, 0, stream>>>(h16, WdT1, bd1, t16, N, 512, 512);
  dim3 gd((N + 127) / 128, 1);
  gemm_f16<false, true><<<gd, gb, 0, stream>>>(t16, WdT2, bd2, d_out, N, 512, 64);
}

// Round 2
// 1076.856 us; speedup vs baseline: 2.9084x; 2.9084x over previous
//
#include <hip/hip_runtime.h>
#include <hip/hip_fp16.h>

typedef _Float16 half8 __attribute__((ext_vector_type(8)));
typedef float f32x4 __attribute__((ext_vector_type(4)));

// ---------------- small utility kernels ----------------

__global__ void to_f16_kernel(const float* __restrict__ A, _Float16* __restrict__ B, int n) {
  int i = blockIdx.x * 256 + threadIdx.x;
  if (i < n) B[i] = (_Float16)A[i];
}

// WT[n*K+k] = W[k*N+n]  (weights stored transposed so GEMM B-staging is coalesced)
__global__ void transpose_f16_kernel(const float* __restrict__ W, _Float16* __restrict__ WT, int K, int N) {
  int i = blockIdx.x * 256 + threadIdx.x;
  if (i >= K * N) return;
  int n = i / K, k = i - n * K;
  WT[i] = (_Float16)W[(size_t)k * N + n];
}

__global__ void transpose_f32_kernel(const float* __restrict__ W, float* __restrict__ WT, int K, int N) {
  int i = blockIdx.x * 256 + threadIdx.x;
  if (i >= K * N) return;
  int n = i / K, k = i - n * K;
  WT[i] = W[(size_t)k * N + n];
}

// in-degree histogram + per-dst edge_attr sum (for self-loop fill_value='mean')
__global__ void edge_hist_kernel(const int* __restrict__ dst0, const float* __restrict__ ea,
                                 int* __restrict__ deg, float* __restrict__ lsum, int E) {
  int i = blockIdx.x * 256 + threadIdx.x;
  if (i >= E * 16) return;
  int e = i >> 4, k = i & 15;
  int d = dst0[e];
  if (k == 0) atomicAdd(&deg[d], 1);
  atomicAdd(&lsum[(size_t)d * 16 + k], ea[i]);
}

__global__ void loop_norm_kernel(const float* __restrict__ lsum, const int* __restrict__ deg,
                                 float* __restrict__ lattr, int N) {
  int i = blockIdx.x * 256 + threadIdx.x;
  if (i >= N * 16) return;
  float c = (float)deg[i >> 4];
  lattr[i] = lsum[i] / fmaxf(c, 1.0f);
}

// exclusive scan of (deg[v]+1) -> offs[0..N], single block
__global__ __launch_bounds__(1024) void scan_kernel(const int* __restrict__ deg, int* __restrict__ offs, int N) {
  __shared__ int part[1024];
  int t = threadIdx.x;
  int chunk = (N + 1023) / 1024;
  int b = t * chunk, e = min(b + chunk, N);
  int s = 0;
  for (int i = b; i < e; i++) s += deg[i] + 1;
  part[t] = s;
  __syncthreads();
  for (int off = 1; off < 1024; off <<= 1) {
    int v = (t >= off) ? part[t - off] : 0;
    __syncthreads();
    part[t] += v;
    __syncthreads();
  }
  int run = (t == 0) ? 0 : part[t - 1];
  for (int i = b; i < e; i++) { offs[i] = run; run += deg[i] + 1; }
  if (t == 1023) offs[N] = part[1023];
}

// scatter real edges into CSR buckets; self-loop edge id E+v appended at slot offs[v]+deg[v]
__global__ void csr_fill_kernel(const int* __restrict__ dst0, const int* __restrict__ offs,
                                const int* __restrict__ deg, int* __restrict__ cnt,
                                int* __restrict__ csr, int E, int N) {
  int i = blockIdx.x * 256 + threadIdx.x;
  if (i < E) {
    int d = dst0[i];
    int p = offs[d] + atomicAdd(&cnt[d], 1);
    csr[p] = i;
  } else if (i < E + N) {
    int v = i - E;
    csr[offs[v] + deg[v]] = E + v;
  }
}

// ---------------- GEMM: C[M,N] = A[M,K](f16) * B (given as BT[N,K] f16) + bias ----------------
// 128x128 tile, 4 waves (2x2), each wave 64x64 via 4x4 mfma_f32_16x16x32_f16.
template <bool RELU, bool OUT_F32>
__global__ __launch_bounds__(256) void gemm_f16(const _Float16* __restrict__ A,
                                                const _Float16* __restrict__ BT,
                                                const float* __restrict__ bias,
                                                void* __restrict__ C,
                                                int M, int K, int Nfull) {
  __shared__ _Float16 As[128 * 40];  // row stride 40 halves (80B, keeps 16B align, breaks bank stride)
  __shared__ _Float16 Bs[128 * 40];
  int t = threadIdx.x;
  int m0 = blockIdx.x * 128;
  int n0 = blockIdx.y * 128;
  int l = t & 63, w = t >> 6;
  int wm = w & 1, wn = w >> 1;
  int lr = l & 15, lq = l >> 4;

  f32x4 acc[4][4];
#pragma unroll
  for (int i = 0; i < 4; i++)
#pragma unroll
    for (int j = 0; j < 4; j++) acc[i][j] = (f32x4){0.f, 0.f, 0.f, 0.f};

  const half8 hzero = {0, 0, 0, 0, 0, 0, 0, 0};
  int srow = t >> 2;            // staging row 0..63 (+64 for second chunk)
  int sq = (t & 3) * 8;         // staging k-offset in halves

  for (int kk = 0; kk < K; kk += 32) {
    half8 a0 = (m0 + srow < M) ? *(const half8*)(A + (size_t)(m0 + srow) * K + kk + sq) : hzero;
    half8 a1 = (m0 + srow + 64 < M) ? *(const half8*)(A + (size_t)(m0 + srow + 64) * K + kk + sq) : hzero;
    half8 b0 = (n0 + srow < Nfull) ? *(const half8*)(BT + (size_t)(n0 + srow) * K + kk + sq) : hzero;
    half8 b1 = (n0 + srow + 64 < Nfull) ? *(const half8*)(BT + (size_t)(n0 + srow + 64) * K + kk + sq) : hzero;
    __syncthreads();
    *(half8*)&As[srow * 40 + sq] = a0;
    *(half8*)&As[(srow + 64) * 40 + sq] = a1;
    *(half8*)&Bs[srow * 40 + sq] = b0;
    *(half8*)&Bs[(srow + 64) * 40 + sq] = b1;
    __syncthreads();
    half8 af[4], bf[4];
#pragma unroll
    for (int mi = 0; mi < 4; mi++) af[mi] = *(const half8*)&As[(wm * 64 + mi * 16 + lr) * 40 + lq * 8];
#pragma unroll
    for (int ni = 0; ni < 4; ni++) bf[ni] = *(const half8*)&Bs[(wn * 64 + ni * 16 + lr) * 40 + lq * 8];
#pragma unroll
    for (int mi = 0; mi < 4; mi++)
#pragma unroll
      for (int ni = 0; ni < 4; ni++)
        acc[mi][ni] = __builtin_amdgcn_mfma_f32_16x16x32_f16(af[mi], bf[ni], acc[mi][ni], 0, 0, 0);
  }

#pragma unroll
  for (int ni = 0; ni < 4; ni++) {
    int col = n0 + wn * 64 + ni * 16 + lr;
    if (col >= Nfull) continue;
    float bv = bias[col];
#pragma unroll
    for (int mi = 0; mi < 4; mi++) {
#pragma unroll
      for (int r = 0; r < 4; r++) {
        int row = m0 + wm * 64 + mi * 16 + lq * 4 + r;
        if (row >= M) continue;
        float v = acc[mi][ni][r] + bv;
        if (RELU) v = fmaxf(v, 0.f);
        if (OUT_F32) ((float*)C)[(size_t)row * Nfull + col] = v;
        else ((_Float16*)C)[(size_t)row * Nfull + col] = (_Float16)v;
      }
    }
  }
}

// ---------------- edge logits: grid-stride, We/att preloaded in registers ----------------
// logits[e,h] = sum_c att[h,c] * lrelu(xl[src,h,c] + xr[dst,h,c] + (ea[e] @ We)[h,c])
// Each wave owns channel fragment c0 = lane*8 (fixed) -> We fragment lives in VGPRs
// across the whole edge loop. Per edge: 2 coalesced row gathers + one 64B broadcast.
__global__ __launch_bounds__(256, 2) void logits_kernel(
    const _Float16* __restrict__ xl, const _Float16* __restrict__ xr,
    const int* __restrict__ src0, const int* __restrict__ dst0,
    const float* __restrict__ ea, const float* __restrict__ lattr,
    const float* __restrict__ WeT, const float* __restrict__ att,
    float* __restrict__ logits, int E, int EP) {
  int l = threadIdx.x & 63;
  int h = l >> 4;
  int c0 = l * 8;

  // per-lane invariant fragments
  float Wf[8][16];
#pragma unroll
  for (int j = 0; j < 8; j++) {
    const float* wr = WeT + (size_t)(c0 + j) * 16;
#pragma unroll
    for (int k = 0; k < 16; k++) Wf[j][k] = wr[k];
  }
  float attf[8];
  const float* attp = att + h * 128 + (l & 15) * 8;
#pragma unroll
  for (int j = 0; j < 8; j++) attf[j] = attp[j];

  int wid = blockIdx.x * 4 + (threadIdx.x >> 6);
  int nw = gridDim.x * 4;

  for (int e = wid; e < EP; e += nw) {
    int s, d;
    const float* eap;
    if (e < E) { s = src0[e]; d = dst0[e]; eap = ea + (size_t)e * 16; }
    else { s = e - E; d = s; eap = lattr + (size_t)(e - E) * 16; }
    half8 a = *(const half8*)(xl + (size_t)s * 512 + c0);
    half8 b = *(const half8*)(xr + (size_t)d * 512 + c0);
    float eav[16];
#pragma unroll
    for (int k = 0; k < 16; k++) eav[k] = eap[k];
    float partial = 0.f;
#pragma unroll
    for (int j = 0; j < 8; j++) {
      float ef = 0.f;
#pragma unroll
      for (int k = 0; k < 16; k++) ef += eav[k] * Wf[j][k];
      float v = (float)a[j] + (float)b[j] + ef;
      v = v > 0.f ? v : 0.2f * v;
      partial += v * attf[j];
    }
#pragma unroll
    for (int off = 1; off < 16; off <<= 1) partial += __shfl_xor(partial, off);
    if ((l & 15) == 0) logits[(size_t)e * 4 + h] = partial;
  }
}

// per-(node,head) softmax max and 1/denominator
__global__ void stats_kernel(const float* __restrict__ logits, const int* __restrict__ csr,
                             const int* __restrict__ offs, float* __restrict__ mx,
                             float* __restrict__ rden, int N) {
  int i = blockIdx.x * 256 + threadIdx.x;
  if (i >= N * 4) return;
  int v = i >> 2, h = i & 3;
  int b = offs[v], e = offs[v + 1];
  float m = -1e30f;
  for (int j = b; j < e; j++) m = fmaxf(m, logits[(size_t)csr[j] * 4 + h]);
  float s = 0.f;
  for (int j = b; j < e; j++) s += __expf(logits[(size_t)csr[j] * 4 + h] - m);
  mx[i] = m;
  rden[i] = 1.0f / (s + 1e-16f);
}

// block-per-node weighted aggregation: h[v,t] = sum_e alpha[e,h] * xl[src(e),t] + bias[t]
__global__ __launch_bounds__(512) void aggregate_kernel(
    const _Float16* __restrict__ xl, const float* __restrict__ logits,
    const float* __restrict__ mx, const float* __restrict__ rden,
    const int* __restrict__ csr, const int* __restrict__ offs,
    const int* __restrict__ src0, const float* __restrict__ bias,
    _Float16* __restrict__ hout, int E) {
  int v = blockIdx.x, t = threadIdx.x;
  int b = offs[v], e = offs[v + 1];
  int h = t >> 7;
  __shared__ float s_a[64 * 4];
  __shared__ int s_s[64];
  float acc = 0.f;
  for (int base = b; base < e; base += 64) {
    int cnt = min(64, e - base);
    if (t < cnt * 4) {
      int j = t >> 2, hh = t & 3;
      int eid = csr[base + j];
      float al = __expf(logits[(size_t)eid * 4 + hh] - mx[v * 4 + hh]) * rden[v * 4 + hh];
      s_a[j * 4 + hh] = al;
      if (hh == 0) s_s[j] = (eid < E) ? src0[eid] : v;
    }
    __syncthreads();
    for (int j = 0; j < cnt; j++)
      acc += s_a[j * 4 + h] * (float)xl[(size_t)s_s[j] * 512 + t];
    __syncthreads();
  }
  hout[(size_t)v * 512 + t] = (_Float16)(acc + bias[t]);
}

// ---------------- launcher ----------------

extern "C" void kernel_launch(void* const* d_in, const int* in_sizes, int n_in,
                              void* d_out, int out_size, void* d_ws, size_t ws_size,
                              hipStream_t stream) {
  (void)n_in; (void)out_size; (void)ws_size;
  const float* x    = (const float*)d_in[0];
  const int*   ei   = (const int*)d_in[1];
  const float* ea   = (const float*)d_in[2];
  const float* Wl1  = (const float*)d_in[3];
  const float* bl1  = (const float*)d_in[4];
  const float* Wr1  = (const float*)d_in[5];
  const float* br1  = (const float*)d_in[6];
  const float* We1  = (const float*)d_in[7];
  const float* att1 = (const float*)d_in[8];
  const float* bias1= (const float*)d_in[9];
  const float* Wl2  = (const float*)d_in[10];
  const float* bl2  = (const float*)d_in[11];
  const float* Wr2  = (const float*)d_in[12];
  const float* br2  = (const float*)d_in[13];
  const float* We2  = (const float*)d_in[14];
  const float* att2 = (const float*)d_in[15];
  const float* bias2= (const float*)d_in[16];
  const float* Wd1  = (const float*)d_in[17];
  const float* bd1  = (const float*)d_in[18];
  const float* Wd2  = (const float*)d_in[19];
  const float* bd2  = (const float*)d_in[20];

  const int N = in_sizes[0] / 128;
  const int E = in_sizes[1] / 2;
  const int EP = E + N;
  const int* src0 = ei;
  const int* dst0 = ei + E;

  char* ws = (char*)d_ws;
  size_t off = 0;
  auto alloc = [&](size_t bytes) -> void* {
    void* p = ws + off;
    off += (bytes + 255) & ~(size_t)255;
    return p;
  };

  // deg | cnt | lsum contiguous -> single memset
  int*   deg   = (int*)alloc((size_t)N * 72);
  int*   cnt   = deg + N;
  float* lsum  = (float*)(cnt + N);
  int*   offs  = (int*)alloc(((size_t)N + 1) * 4);
  int*   csr   = (int*)alloc((size_t)EP * 4);
  float* lattr = (float*)alloc((size_t)N * 64);
  float* logits= (float*)alloc((size_t)EP * 16);
  float* mx    = (float*)alloc((size_t)N * 16);
  float* rden  = (float*)alloc((size_t)N * 16);
  _Float16* x16  = (_Float16*)alloc((size_t)N * 128 * 2);
  _Float16* xl16 = (_Float16*)alloc((size_t)N * 512 * 2);
  _Float16* xr16 = (_Float16*)alloc((size_t)N * 512 * 2);
  _Float16* h16  = (_Float16*)alloc((size_t)N * 512 * 2);
  _Float16* WlT1 = (_Float16*)alloc(128 * 512 * 2);
  _Float16* WrT1 = (_Float16*)alloc(128 * 512 * 2);
  _Float16* WlT2 = (_Float16*)alloc(512 * 512 * 2);
  _Float16* WrT2 = (_Float16*)alloc(512 * 512 * 2);
  _Float16* WdT1 = (_Float16*)alloc(512 * 512 * 2);
  _Float16* WdT2 = (_Float16*)alloc(512 * 64 * 2);
  float* WeT1 = (float*)alloc(16 * 512 * 4);
  float* WeT2 = (float*)alloc(16 * 512 * 4);
  _Float16* t16 = xr16;  // decoder hidden reuses xr buffer (dead by then)

  hipMemsetAsync(deg, 0, (size_t)N * 72, stream);

  int g;
  g = (N * 128 + 255) / 256; to_f16_kernel<<<g, 256, 0, stream>>>(x, x16, N * 128);
  g = (128 * 512 + 255) / 256;
  transpose_f16_kernel<<<g, 256, 0, stream>>>(Wl1, WlT1, 128, 512);
  transpose_f16_kernel<<<g, 256, 0, stream>>>(Wr1, WrT1, 128, 512);
  g = (512 * 512 + 255) / 256;
  transpose_f16_kernel<<<g, 256, 0, stream>>>(Wl2, WlT2, 512, 512);
  transpose_f16_kernel<<<g, 256, 0, stream>>>(Wr2, WrT2, 512, 512);
  transpose_f16_kernel<<<g, 256, 0, stream>>>(Wd1, WdT1, 512, 512);
  g = (512 * 64 + 255) / 256;
  transpose_f16_kernel<<<g, 256, 0, stream>>>(Wd2, WdT2, 512, 64);
  g = (16 * 512 + 255) / 256;
  transpose_f32_kernel<<<g, 256, 0, stream>>>(We1, WeT1, 16, 512);
  transpose_f32_kernel<<<g, 256, 0, stream>>>(We2, WeT2, 16, 512);

  dim3 gg((N + 127) / 128, 4), gb(256);
  gemm_f16<false, false><<<gg, gb, 0, stream>>>(x16, WlT1, bl1, xl16, N, 128, 512);
  gemm_f16<false, false><<<gg, gb, 0, stream>>>(x16, WrT1, br1, xr16, N, 128, 512);

  g = (E * 16 + 255) / 256; edge_hist_kernel<<<g, 256, 0, stream>>>(dst0, ea, deg, lsum, E);
  g = (N * 16 + 255) / 256; loop_norm_kernel<<<g, 256, 0, stream>>>(lsum, deg, lattr, N);
  scan_kernel<<<1, 1024, 0, stream>>>(deg, offs, N);
  g = (EP + 255) / 256; csr_fill_kernel<<<g, 256, 0, stream>>>(dst0, offs, deg, cnt, csr, E, N);

  const int LGRID = 512;  // grid-stride: ~160 edges/wave amortizes the 128-reg We preload

  // ---- GAT layer 1 ----
  logits_kernel<<<LGRID, 256, 0, stream>>>(xl16, xr16, src0, dst0, ea, lattr, WeT1, att1, logits, E, EP);
  g = (N * 4 + 255) / 256; stats_kernel<<<g, 256, 0, stream>>>(logits, csr, offs, mx, rden, N);
  aggregate_kernel<<<N, 512, 0, stream>>>(xl16, logits, mx, rden, csr, offs, src0, bias1, h16, E);

  // ---- GAT layer 2 ----
  gemm_f16<false, false><<<gg, gb, 0, stream>>>(h16, WlT2, bl2, xl16, N, 512, 512);
  gemm_f16<false, false><<<gg, gb, 0, stream>>>(h16, WrT2, br2, xr16, N, 512, 512);
  logits_kernel<<<LGRID, 256, 0, stream>>>(xl16, xr16, src0, dst0, ea, lattr, WeT2, att2, logits, E, EP);
  g = (N * 4 + 255) / 256; stats_kernel<<<g, 256, 0, stream>>>(logits, csr, offs, mx, rden, N);
  aggregate_kernel<<<N, 512, 0, stream>>>(xl16, logits, mx, rden, csr, offs, src0, bias2, h16, E);

  // ---- decoder ----
  gemm_f16<true, false><<<gg, gb, 0, stream>>>(h16, WdT1, bd1, t16, N, 512, 512);
  dim3 gd((N + 127) / 128, 1);
  gemm_f16<false, true><<<gd, gb, 0, stream>>>(t16, WdT2, bd2, d_out, N, 512, 64);
}

// Round 3
// 793.365 us; speedup vs baseline: 3.9477x; 1.3573x over previous
//
#include <hip/hip_runtime.h>
#include <hip/hip_fp16.h>

typedef _Float16 half8 __attribute__((ext_vector_type(8)));
typedef _Float16 half2v __attribute__((ext_vector_type(2)));
typedef float f32x4 __attribute__((ext_vector_type(4)));

#if __has_builtin(__builtin_amdgcn_fdot2)
#define FDOT2(a, b, c) __builtin_amdgcn_fdot2((a), (b), (c), false)
#else
static __device__ __forceinline__ float FDOT2(half2v a, half2v b, float c) {
  return (float)a[0] * (float)b[0] + (float)a[1] * (float)b[1] + c;
}
#endif
#define H2(v8, p) ((half2v){(v8)[2 * (p)], (v8)[2 * (p) + 1]})

// ---------------- small utility kernels ----------------

__global__ void to_f16_kernel(const float* __restrict__ A, _Float16* __restrict__ B, int n) {
  int i = blockIdx.x * 256 + threadIdx.x;
  if (i < n) B[i] = (_Float16)A[i];
}

// WT[n*K+k] = W[k*N+n]
__global__ void transpose_f16_kernel(const float* __restrict__ W, _Float16* __restrict__ WT, int K, int N) {
  int i = blockIdx.x * 256 + threadIdx.x;
  if (i >= K * N) return;
  int n = i / K, k = i - n * K;
  WT[i] = (_Float16)W[(size_t)k * N + n];
}

// in-degree histogram + per-dst edge_attr sum (for self-loop fill_value='mean')
__global__ void edge_hist_kernel(const int* __restrict__ dst0, const float* __restrict__ ea,
                                 int* __restrict__ deg, float* __restrict__ lsum, int E) {
  int i = blockIdx.x * 256 + threadIdx.x;
  if (i >= E * 16) return;
  int e = i >> 4, k = i & 15;
  int d = dst0[e];
  if (k == 0) atomicAdd(&deg[d], 1);
  atomicAdd(&lsum[(size_t)d * 16 + k], ea[i]);
}

// self-loop attr -> f16, written into ea16[E..E+N)
__global__ void loop_norm16_kernel(const float* __restrict__ lsum, const int* __restrict__ deg,
                                   _Float16* __restrict__ dst16, int N) {
  int i = blockIdx.x * 256 + threadIdx.x;
  if (i >= N * 16) return;
  float c = (float)deg[i >> 4];
  dst16[i] = (_Float16)(lsum[i] / fmaxf(c, 1.0f));
}

// exclusive scan of (deg[v]+1) -> offs[0..N], single block
__global__ __launch_bounds__(1024) void scan_kernel(const int* __restrict__ deg, int* __restrict__ offs, int N) {
  __shared__ int part[1024];
  int t = threadIdx.x;
  int chunk = (N + 1023) / 1024;
  int b = t * chunk, e = min(b + chunk, N);
  int s = 0;
  for (int i = b; i < e; i++) s += deg[i] + 1;
  part[t] = s;
  __syncthreads();
  for (int off = 1; off < 1024; off <<= 1) {
    int v = (t >= off) ? part[t - off] : 0;
    __syncthreads();
    part[t] += v;
    __syncthreads();
  }
  int run = (t == 0) ? 0 : part[t - 1];
  for (int i = b; i < e; i++) { offs[i] = run; run += deg[i] + 1; }
  if (t == 1023) offs[N] = part[1023];
}

// scatter (eid, src) into CSR buckets; self-loop eid=E+v at slot offs[v]+deg[v]; +2 pad
__global__ void csr_fill_kernel(const int* __restrict__ src0, const int* __restrict__ dst0,
                                const int* __restrict__ offs, const int* __restrict__ deg,
                                int* __restrict__ cnt, int* __restrict__ csr_eid,
                                int* __restrict__ csr_src, int E, int N) {
  int i = blockIdx.x * 256 + threadIdx.x;
  if (i == 0) {
    int EP = E + N;
    csr_eid[EP] = 0; csr_eid[EP + 1] = 0;
    csr_src[EP] = 0; csr_src[EP + 1] = 0;
  }
  if (i < E) {
    int d = dst0[i];
    int p = offs[d] + atomicAdd(&cnt[d], 1);
    csr_eid[p] = i;
    csr_src[p] = src0[i];
  } else if (i < E + N) {
    int v = i - E;
    int p = offs[v] + deg[v];
    csr_eid[p] = E + v;
    csr_src[p] = v;
  }
}

// ---------------- GEMM: C[M,N] = A[M,K](f16) * BT[N,K](f16) + bias ----------------
template <bool RELU, bool OUT_F32>
__global__ __launch_bounds__(256) void gemm_f16(const _Float16* __restrict__ A,
                                                const _Float16* __restrict__ BT,
                                                const float* __restrict__ bias,
                                                void* __restrict__ C,
                                                int M, int K, int Nfull) {
  __shared__ _Float16 As[128 * 40];
  __shared__ _Float16 Bs[128 * 40];
  int t = threadIdx.x;
  int m0 = blockIdx.x * 128;
  int n0 = blockIdx.y * 128;
  int l = t & 63, w = t >> 6;
  int wm = w & 1, wn = w >> 1;
  int lr = l & 15, lq = l >> 4;

  f32x4 acc[4][4];
#pragma unroll
  for (int i = 0; i < 4; i++)
#pragma unroll
    for (int j = 0; j < 4; j++) acc[i][j] = (f32x4){0.f, 0.f, 0.f, 0.f};

  const half8 hzero = {0, 0, 0, 0, 0, 0, 0, 0};
  int srow = t >> 2;
  int sq = (t & 3) * 8;

  for (int kk = 0; kk < K; kk += 32) {
    half8 a0 = (m0 + srow < M) ? *(const half8*)(A + (size_t)(m0 + srow) * K + kk + sq) : hzero;
    half8 a1 = (m0 + srow + 64 < M) ? *(const half8*)(A + (size_t)(m0 + srow + 64) * K + kk + sq) : hzero;
    half8 b0 = (n0 + srow < Nfull) ? *(const half8*)(BT + (size_t)(n0 + srow) * K + kk + sq) : hzero;
    half8 b1 = (n0 + srow + 64 < Nfull) ? *(const half8*)(BT + (size_t)(n0 + srow + 64) * K + kk + sq) : hzero;
    __syncthreads();
    *(half8*)&As[srow * 40 + sq] = a0;
    *(half8*)&As[(srow + 64) * 40 + sq] = a1;
    *(half8*)&Bs[srow * 40 + sq] = b0;
    *(half8*)&Bs[(srow + 64) * 40 + sq] = b1;
    __syncthreads();
    half8 af[4], bf[4];
#pragma unroll
    for (int mi = 0; mi < 4; mi++) af[mi] = *(const half8*)&As[(wm * 64 + mi * 16 + lr) * 40 + lq * 8];
#pragma unroll
    for (int ni = 0; ni < 4; ni++) bf[ni] = *(const half8*)&Bs[(wn * 64 + ni * 16 + lr) * 40 + lq * 8];
#pragma unroll
    for (int mi = 0; mi < 4; mi++)
#pragma unroll
      for (int ni = 0; ni < 4; ni++)
        acc[mi][ni] = __builtin_amdgcn_mfma_f32_16x16x32_f16(af[mi], bf[ni], acc[mi][ni], 0, 0, 0);
  }

#pragma unroll
  for (int ni = 0; ni < 4; ni++) {
    int col = n0 + wn * 64 + ni * 16 + lr;
    if (col >= Nfull) continue;
    float bv = bias[col];
#pragma unroll
    for (int mi = 0; mi < 4; mi++) {
#pragma unroll
      for (int r = 0; r < 4; r++) {
        int row = m0 + wm * 64 + mi * 16 + lq * 4 + r;
        if (row >= M) continue;
        float v = acc[mi][ni][r] + bv;
        if (RELU) v = fmaxf(v, 0.f);
        if (OUT_F32) ((float*)C)[(size_t)row * Nfull + col] = v;
        else ((_Float16*)C)[(size_t)row * Nfull + col] = (_Float16)v;
      }
    }
  }
}

// ---------------- fused GATv2 edge pass: wave per node, online softmax ----------------
// Per node v (one wave): iterate CSR edges, compute logit(e) = att_h . lrelu(xl[s]+xr[v]+ea[e]@We),
// online-softmax accumulate acc_h += alpha * xl[s].  One xl-row gather per edge (vs 2 before),
// no logits/stats round-trips.  We fragment: f16 packed, 64 VGPRs, resident.
__global__ __launch_bounds__(256, 2) void gat_fused_kernel(
    const _Float16* __restrict__ xl, const _Float16* __restrict__ xr,
    const int* __restrict__ csr_eid, const int* __restrict__ csr_src,
    const int* __restrict__ offs,
    const _Float16* __restrict__ ea16,   // [E+N][16]
    const _Float16* __restrict__ WeP,    // [512][16]  (WeP[c][k] = We[k][c])
    const float* __restrict__ att, const float* __restrict__ bias,
    _Float16* __restrict__ hout, int N) {
  int l = threadIdx.x & 63;
  int h = l >> 4;
  int c0 = l * 8;

  half8 Wf0[8], Wf1[8];
#pragma unroll
  for (int j = 0; j < 8; j++) {
    Wf0[j] = *(const half8*)(WeP + (size_t)(c0 + j) * 16);
    Wf1[j] = *(const half8*)(WeP + (size_t)(c0 + j) * 16 + 8);
  }
  float attf[8];
  const float* attp = att + h * 128 + (l & 15) * 8;
#pragma unroll
  for (int j = 0; j < 8; j++) attf[j] = attp[j];

  int wid = blockIdx.x * 4 + (threadIdx.x >> 6);
  int nw = gridDim.x * 4;

  for (int v = wid; v < N; v += nw) {
    int b = offs[v], e2 = offs[v + 1];
    half8 xrv = *(const half8*)(xr + (size_t)v * 512 + c0);
    // pipeline: gather regs for edge j; indices resolved for edge j+1
    int sB = csr_src[b], eB = csr_eid[b];
    half8 xsA = *(const half8*)(xl + (size_t)sB * 512 + c0);
    half8 ea0A = *(const half8*)(ea16 + (size_t)eB * 16);
    half8 ea1A = *(const half8*)(ea16 + (size_t)eB * 16 + 8);
    sB = csr_src[b + 1]; eB = csr_eid[b + 1];

    float m = -1e30f, den = 0.f;
    float acc[8];
#pragma unroll
    for (int j = 0; j < 8; j++) acc[j] = 0.f;

    for (int j = b; j < e2; j++) {
      half8 xs = xsA, ea0 = ea0A, ea1 = ea1A;
      // issue next edge's gathers (indices already resolved), then resolve j+2 indices
      xsA = *(const half8*)(xl + (size_t)sB * 512 + c0);
      ea0A = *(const half8*)(ea16 + (size_t)eB * 16);
      ea1A = *(const half8*)(ea16 + (size_t)eB * 16 + 8);
      sB = csr_src[j + 2]; eB = csr_eid[j + 2];   // padded arrays: safe

      float partial = 0.f;
#pragma unroll
      for (int jj = 0; jj < 8; jj++) {
        float ef = 0.f;
#pragma unroll
        for (int p = 0; p < 4; p++) ef = FDOT2(H2(ea0, p), H2(Wf0[jj], p), ef);
#pragma unroll
        for (int p = 0; p < 4; p++) ef = FDOT2(H2(ea1, p), H2(Wf1[jj], p), ef);
        float val = (float)xs[jj] + (float)xrv[jj] + ef;
        val = val > 0.f ? val : 0.2f * val;
        partial = fmaf(val, attf[jj], partial);
      }
#pragma unroll
      for (int off2 = 1; off2 < 16; off2 <<= 1) partial += __shfl_xor(partial, off2);
      // online softmax (per head; all 16 lanes of the head group agree on `partial`)
      float mn = fmaxf(m, partial);
      float sc = __expf(m - mn);
      float al = __expf(partial - mn);
      den = den * sc + al;
#pragma unroll
      for (int jj = 0; jj < 8; jj++) acc[jj] = acc[jj] * sc + al * (float)xs[jj];
      m = mn;
    }
    float rd = 1.f / (den + 1e-16f);
    half8 o;
#pragma unroll
    for (int jj = 0; jj < 8; jj++) o[jj] = (_Float16)(acc[jj] * rd + bias[c0 + jj]);
    *(half8*)(hout + (size_t)v * 512 + c0) = o;
  }
}

// ---------------- launcher ----------------

extern "C" void kernel_launch(void* const* d_in, const int* in_sizes, int n_in,
                              void* d_out, int out_size, void* d_ws, size_t ws_size,
                              hipStream_t stream) {
  (void)n_in; (void)out_size; (void)ws_size;
  const float* x    = (const float*)d_in[0];
  const int*   ei   = (const int*)d_in[1];
  const float* ea   = (const float*)d_in[2];
  const float* Wl1  = (const float*)d_in[3];
  const float* bl1  = (const float*)d_in[4];
  const float* Wr1  = (const float*)d_in[5];
  const float* br1  = (const float*)d_in[6];
  const float* We1  = (const float*)d_in[7];
  const float* att1 = (const float*)d_in[8];
  const float* bias1= (const float*)d_in[9];
  const float* Wl2  = (const float*)d_in[10];
  const float* bl2  = (const float*)d_in[11];
  const float* Wr2  = (const float*)d_in[12];
  const float* br2  = (const float*)d_in[13];
  const float* We2  = (const float*)d_in[14];
  const float* att2 = (const float*)d_in[15];
  const float* bias2= (const float*)d_in[16];
  const float* Wd1  = (const float*)d_in[17];
  const float* bd1  = (const float*)d_in[18];
  const float* Wd2  = (const float*)d_in[19];
  const float* bd2  = (const float*)d_in[20];

  const int N = in_sizes[0] / 128;
  const int E = in_sizes[1] / 2;
  const int EP = E + N;
  const int* src0 = ei;
  const int* dst0 = ei + E;

  char* ws = (char*)d_ws;
  size_t off = 0;
  auto alloc = [&](size_t bytes) -> void* {
    void* p = ws + off;
    off += (bytes + 255) & ~(size_t)255;
    return p;
  };

  // deg | cnt | lsum contiguous -> single memset
  int*   deg   = (int*)alloc((size_t)N * 72);
  int*   cnt   = deg + N;
  float* lsum  = (float*)(cnt + N);
  int*   offs  = (int*)alloc(((size_t)N + 1) * 4);
  int*   csr_eid = (int*)alloc(((size_t)EP + 2) * 4);
  int*   csr_src = (int*)alloc(((size_t)EP + 2) * 4);
  _Float16* ea16 = (_Float16*)alloc((size_t)EP * 16 * 2);
  _Float16* x16  = (_Float16*)alloc((size_t)N * 128 * 2);
  _Float16* xl16 = (_Float16*)alloc((size_t)N * 512 * 2);
  _Float16* xr16 = (_Float16*)alloc((size_t)N * 512 * 2);
  _Float16* h16  = (_Float16*)alloc((size_t)N * 512 * 2);
  _Float16* WlT1 = (_Float16*)alloc(128 * 512 * 2);
  _Float16* WrT1 = (_Float16*)alloc(128 * 512 * 2);
  _Float16* WlT2 = (_Float16*)alloc(512 * 512 * 2);
  _Float16* WrT2 = (_Float16*)alloc(512 * 512 * 2);
  _Float16* WdT1 = (_Float16*)alloc(512 * 512 * 2);
  _Float16* WdT2 = (_Float16*)alloc(512 * 64 * 2);
  _Float16* WeP1 = (_Float16*)alloc(512 * 16 * 2);
  _Float16* WeP2 = (_Float16*)alloc(512 * 16 * 2);
  _Float16* t16 = xr16;  // decoder hidden reuses xr buffer (dead by then)

  hipMemsetAsync(deg, 0, (size_t)N * 72, stream);

  int g;
  g = (N * 128 + 255) / 256; to_f16_kernel<<<g, 256, 0, stream>>>(x, x16, N * 128);
  g = (E * 16 + 255) / 256;  to_f16_kernel<<<g, 256, 0, stream>>>(ea, ea16, E * 16);
  g = (128 * 512 + 255) / 256;
  transpose_f16_kernel<<<g, 256, 0, stream>>>(Wl1, WlT1, 128, 512);
  transpose_f16_kernel<<<g, 256, 0, stream>>>(Wr1, WrT1, 128, 512);
  g = (512 * 512 + 255) / 256;
  transpose_f16_kernel<<<g, 256, 0, stream>>>(Wl2, WlT2, 512, 512);
  transpose_f16_kernel<<<g, 256, 0, stream>>>(Wr2, WrT2, 512, 512);
  transpose_f16_kernel<<<g, 256, 0, stream>>>(Wd1, WdT1, 512, 512);
  g = (512 * 64 + 255) / 256;
  transpose_f16_kernel<<<g, 256, 0, stream>>>(Wd2, WdT2, 512, 64);
  g = (16 * 512 + 255) / 256;
  transpose_f16_kernel<<<g, 256, 0, stream>>>(We1, WeP1, 16, 512);
  transpose_f16_kernel<<<g, 256, 0, stream>>>(We2, WeP2, 16, 512);

  dim3 gg((N + 127) / 128, 4), gb(256);
  gemm_f16<false, false><<<gg, gb, 0, stream>>>(x16, WlT1, bl1, xl16, N, 128, 512);
  gemm_f16<false, false><<<gg, gb, 0, stream>>>(x16, WrT1, br1, xr16, N, 128, 512);

  g = (E * 16 + 255) / 256; edge_hist_kernel<<<g, 256, 0, stream>>>(dst0, ea, deg, lsum, E);
  g = (N * 16 + 255) / 256; loop_norm16_kernel<<<g, 256, 0, stream>>>(lsum, deg, ea16 + (size_t)E * 16, N);
  scan_kernel<<<1, 1024, 0, stream>>>(deg, offs, N);
  g = (EP + 255) / 256;
  csr_fill_kernel<<<g, 256, 0, stream>>>(src0, dst0, offs, deg, cnt, csr_eid, csr_src, E, N);

  const int FGRID = 512;  // 2 blocks/CU resident; grid-stride over nodes

  // ---- GAT layer 1 (fused logits+softmax+aggregate) ----
  gat_fused_kernel<<<FGRID, 256, 0, stream>>>(xl16, xr16, csr_eid, csr_src, offs,
                                              ea16, WeP1, att1, bias1, h16, N);

  // ---- GAT layer 2 ----
  gemm_f16<false, false><<<gg, gb, 0, stream>>>(h16, WlT2, bl2, xl16, N, 512, 512);
  gemm_f16<false, false><<<gg, gb, 0, stream>>>(h16, WrT2, br2, xr16, N, 512, 512);
  gat_fused_kernel<<<FGRID, 256, 0, stream>>>(xl16, xr16, csr_eid, csr_src, offs,
                                              ea16, WeP2, att2, bias2, h16, N);

  // ---- decoder ----
  gemm_f16<true, false><<<gg, gb, 0, stream>>>(h16, WdT1, bd1, t16, N, 512, 512);
  dim3 gd((N + 127) / 128, 1);
  gemm_f16<false, true><<<gd, gb, 0, stream>>>(t16, WdT2, bd2, d_out, N, 512, 64);
}